// Round 1
// baseline (96.517 us; speedup 1.0000x reference)
//
#include <hip/hip_runtime.h>

#define RSQRT2 0.70710678118654752440f

__global__ __launch_bounds__(256) void amp_kernel(
    const float* __restrict__ a1, const float* __restrict__ b1, const float* __restrict__ g1,
    const float* __restrict__ a2, const float* __restrict__ b2, const float* __restrict__ g2,
    const float* __restrict__ mI, const float* __restrict__ m0, const float* __restrict__ g0,
    const float* __restrict__ cr, const float* __restrict__ ci,
    float* __restrict__ out, int N)
{
    const int n = blockIdx.x * blockDim.x + threadIdx.x;
    if (n >= N) return;

    // F[a][c] : coherent sum over resonances, a = lambda_A index (m1=-1,0,1),
    // c = delta index (delta = -1,0,1)
    float Fre[3][3], Fim[3][3];
    #pragma unroll
    for (int a = 0; a < 3; ++a)
        #pragma unroll
        for (int c = 0; c < 3; ++c) { Fre[a][c] = 0.f; Fim[a][c] = 0.f; }

    #pragma unroll
    for (int r = 0; r < 4; ++r) {
        const int idx = r * N + n;
        const float A1 = a1[idx];
        const float B1 = b1[idx];
        const float G1 = g1[idx];
        const float A2 = a2[idx];
        const float B2 = b2[idx];
        const float G2 = g2[idx];
        const float mm = mI[idx];

        float sA, cA; __sincosf(A1,      &sA, &cA);   // e^{i m1 alpha1}
        float sP, cP; __sincosf(G1 + A2, &sP, &cP);   // e^{i x (gamma1+alpha2)}
        float sG, cG; __sincosf(G2,      &sG, &cG);   // e^{i delta gamma2}

        // Wigner small-d, j=1: rows m1=-1,0,1 / cols m2=-1,0,1
        float sb, cb; __sincosf(B1, &sb, &cb);
        float d1[3][3];
        d1[0][0] = 0.5f * (1.f + cb); d1[0][1] = -RSQRT2 * sb; d1[0][2] = 0.5f * (1.f - cb);
        d1[1][0] =  RSQRT2 * sb;      d1[1][1] = cb;           d1[1][2] = -RSQRT2 * sb;
        d1[2][0] = 0.5f * (1.f - cb); d1[2][1] =  RSQRT2 * sb; d1[2][2] = 0.5f * (1.f + cb);

        __sincosf(B2, &sb, &cb);
        float d2[3][3];
        d2[0][0] = 0.5f * (1.f + cb); d2[0][1] = -RSQRT2 * sb; d2[0][2] = 0.5f * (1.f - cb);
        d2[1][0] =  RSQRT2 * sb;      d2[1][1] = cb;           d2[1][2] = -RSQRT2 * sb;
        d2[2][0] = 0.5f * (1.f - cb); d2[2][1] =  RSQRT2 * sb; d2[2][2] = 0.5f * (1.f + cb);

        // W = coef[r] * BW(r,n);  1/(x - i y) = (x + i y) / (x^2 + y^2)
        const float m0r = m0[r], g0r = g0[r];
        const float x = m0r * m0r - mm * mm;
        const float y = m0r * g0r;
        const float inv = __builtin_amdgcn_rcpf(x * x + y * y);
        const float bre = x * inv, bim = y * inv;
        float sc, cc; __sincosf(ci[r], &sc, &cc);
        const float c_re = cr[r] * cc, c_im = cr[r] * sc;
        const float Wre = c_re * bre - c_im * bim;
        const float Wim = c_re * bim + c_im * bre;

        // WA[a] = W * e^{i (a-1) alpha1}
        float WAre[3], WAim[3];
        WAre[1] = Wre;                 WAim[1] = Wim;
        WAre[2] = Wre * cA - Wim * sA; WAim[2] = Wre * sA + Wim * cA;
        WAre[0] = Wre * cA + Wim * sA; WAim[0] = Wim * cA - Wre * sA;

        #pragma unroll
        for (int a = 0; a < 3; ++a) {
            #pragma unroll
            for (int c = 0; c < 3; ++c) {
                // M[a][c] = sum_x d1[a][x] e^{i x phi} d2[x][c]
                const float P0 = d1[a][0] * d2[0][c];
                const float P1 = d1[a][1] * d2[1][c];
                const float P2 = d1[a][2] * d2[2][c];
                const float Mre = cP * (P0 + P2) + P1;
                const float Mim = sP * (P2 - P0);
                // q = WA[a] * e^{i (c-1) gamma2}
                float qre, qim;
                if (c == 1)      { qre = WAre[a];                     qim = WAim[a]; }
                else if (c == 2) { qre = WAre[a]*cG - WAim[a]*sG;     qim = WAre[a]*sG + WAim[a]*cG; }
                else             { qre = WAre[a]*cG + WAim[a]*sG;     qim = WAim[a]*cG - WAre[a]*sG; }
                // F += q * M
                Fre[a][c] += qre * Mre - qim * Mim;
                Fim[a][c] += qre * Mim + qim * Mre;
            }
        }
    }

    // incoherent sum: delta multiplicity = 3 - |delta|  ->  {2, 3, 2}
    float s = 0.f;
    #pragma unroll
    for (int a = 0; a < 3; ++a) {
        s += 2.f * (Fre[a][0] * Fre[a][0] + Fim[a][0] * Fim[a][0]);
        s += 3.f * (Fre[a][1] * Fre[a][1] + Fim[a][1] * Fim[a][1]);
        s += 2.f * (Fre[a][2] * Fre[a][2] + Fim[a][2] * Fim[a][2]);
    }
    out[n] = s;
}

extern "C" void kernel_launch(void* const* d_in, const int* in_sizes, int n_in,
                              void* d_out, int out_size, void* d_ws, size_t ws_size,
                              hipStream_t stream)
{
    const float* a1 = (const float*)d_in[0];
    const float* b1 = (const float*)d_in[1];
    const float* g1 = (const float*)d_in[2];
    const float* a2 = (const float*)d_in[3];
    const float* b2 = (const float*)d_in[4];
    const float* g2 = (const float*)d_in[5];
    const float* m  = (const float*)d_in[6];
    const float* m0 = (const float*)d_in[7];
    const float* g0 = (const float*)d_in[8];
    const float* cr = (const float*)d_in[9];
    const float* ci = (const float*)d_in[10];
    float* out = (float*)d_out;

    const int N = out_size;               // 262144 events
    const int block = 256;
    const int grid = (N + block - 1) / block;
    amp_kernel<<<grid, block, 0, stream>>>(a1, b1, g1, a2, b2, g2, m, m0, g0, cr, ci, out, N);
}

// Round 2
// 94.674 us; speedup vs baseline: 1.0195x; 1.0195x over previous
//
#include <hip/hip_runtime.h>

#define RK 0.70710678118654752440f   // 1/sqrt(2)

__global__ __launch_bounds__(256) void amp_kernel(
    const float* __restrict__ a1, const float* __restrict__ b1, const float* __restrict__ g1,
    const float* __restrict__ a2, const float* __restrict__ b2, const float* __restrict__ g2,
    const float* __restrict__ mI, const float* __restrict__ m0, const float* __restrict__ g0,
    const float* __restrict__ cr, const float* __restrict__ ci,
    float* __restrict__ out, int N)
{
    const int n = blockIdx.x * blockDim.x + threadIdx.x;
    if (n >= N) return;

    // F[a][c]: coherent sum over resonances. a = lambda_A idx (m1=-1,0,1),
    // c = delta idx (delta=-1,0,1).
    float Fre[3][3], Fim[3][3];
    #pragma unroll
    for (int a = 0; a < 3; ++a)
        #pragma unroll
        for (int c = 0; c < 3; ++c) { Fre[a][c] = 0.f; Fim[a][c] = 0.f; }

    #pragma unroll
    for (int r = 0; r < 4; ++r) {
        const int idx = r * N + n;
        const float A1 = a1[idx];
        const float B1 = b1[idx];
        const float G1 = g1[idx];
        const float A2 = a2[idx];
        const float B2 = b2[idx];
        const float G2 = g2[idx];
        const float mm = mI[idx];

        float sA, cA; __sincosf(A1,      &sA, &cA);   // e^{i m1 alpha1}
        float sP, cP; __sincosf(G1 + A2, &sP, &cP);   // e^{i x (gamma1+alpha2)}
        float sG, cG; __sincosf(G2,      &sG, &cG);   // e^{i delta gamma2}
        float sb1, cb1; __sincosf(B1, &sb1, &cb1);
        float sb2, cb2; __sincosf(B2, &sb2, &cb2);

        // Wigner small-d j=1 building blocks.
        // d1 row a=0: ( hp1, -ks1, hm1 ); row a=1: ( ks1, cb1, -ks1 )
        // d2 col c=0: ( hp2,  ks2, hm2 ); col c=1: ( -ks2, cb2, ks2 ); col c=2: ( hm2, -ks2, hp2 )
        const float hp1 = 0.5f * (1.f + cb1), hm1 = 0.5f * (1.f - cb1), ks1 = RK * sb1;
        const float hp2 = 0.5f * (1.f + cb2), hm2 = 0.5f * (1.f - cb2), ks2 = RK * sb2;

        // M[a][c] = sum_x d1[a][x] e^{i(x-1)phi} d2[x][c].
        // Symmetry: M[2-a][2-c] = (-1)^(a-c) conj(M[a][c])  -> compute 5 cells.
        float P0, P1, P2;
        P0 = hp1 * hp2;  P1 = -ks1 * ks2;  P2 = hm1 * hm2;
        const float Mre00 = fmaf(cP, P0 + P2, P1), Mim00 = sP * (P2 - P0);
        P0 = -hp1 * ks2; P1 = -ks1 * cb2;  P2 = hm1 * ks2;
        const float Mre01 = fmaf(cP, P0 + P2, P1), Mim01 = sP * (P2 - P0);
        P0 = hp1 * hm2;  P1 =  ks1 * ks2;  P2 = hm1 * hp2;
        const float Mre02 = fmaf(cP, P0 + P2, P1), Mim02 = sP * (P2 - P0);
        P0 = ks1 * hp2;  P1 =  cb1 * ks2;  P2 = -ks1 * hm2;
        const float Mre10 = fmaf(cP, P0 + P2, P1), Mim10 = sP * (P2 - P0);
        // (1,1): P0 = P2 = -0.5 sb1 sb2 -> imag part vanishes
        const float Mre11 = fmaf(-cP * sb1, sb2, cb1 * cb2);

        // W = coef[r] * BW(r,n);  1/(x - i y) = (x + i y)/(x^2 + y^2)
        const float m0r = m0[r], g0r = g0[r];
        const float x = m0r * m0r - mm * mm;
        const float y = m0r * g0r;
        const float inv = __builtin_amdgcn_rcpf(fmaf(x, x, y * y));
        const float bre = x * inv, bim = y * inv;
        float sc, cc; __sincosf(ci[r], &sc, &cc);
        const float c_re = cr[r] * cc, c_im = cr[r] * sc;
        const float Wre = c_re * bre - c_im * bim;
        const float Wim = c_re * bim + c_im * bre;

        // WA[a] = W * e^{i(a-1) alpha1} (shared products)
        const float p1 = Wre * cA, p2 = Wim * sA, p3 = Wre * sA, p4 = Wim * cA;
        float WAre[3], WAim[3];
        WAre[0] = p1 + p2; WAim[0] = p4 - p3;
        WAre[1] = Wre;     WAim[1] = Wim;
        WAre[2] = p1 - p2; WAim[2] = p3 + p4;

        // q[a][c] = WA[a] * E[c], E = { e^{-i g2}, 1, e^{+i g2} } (shared products)
        float qre[3][3], qim[3][3];
        #pragma unroll
        for (int a = 0; a < 3; ++a) {
            const float t1 = WAre[a] * cG, t2 = WAim[a] * sG;
            const float t3 = WAre[a] * sG, t4 = WAim[a] * cG;
            qre[a][0] = t1 + t2; qim[a][0] = t4 - t3;
            qre[a][1] = WAre[a]; qim[a][1] = WAim[a];
            qre[a][2] = t1 - t2; qim[a][2] = t3 + t4;
        }

        // F[a][c] += q[a][c] * M[a][c], derived cells via symmetry:
        //   M22 = conj(M00), M21 = -conj(M01), M20 = conj(M02), M12 = -conj(M10)
        #define CFMA(A, C, MRE, MIM)                                   \
            Fre[A][C] += qre[A][C] * (MRE) - qim[A][C] * (MIM);        \
            Fim[A][C] += qre[A][C] * (MIM) + qim[A][C] * (MRE);
        CFMA(0, 0,  Mre00,  Mim00)
        CFMA(0, 1,  Mre01,  Mim01)
        CFMA(0, 2,  Mre02,  Mim02)
        CFMA(1, 0,  Mre10,  Mim10)
        CFMA(1, 1,  Mre11,  0.f  )
        CFMA(1, 2, -Mre10,  Mim10)
        CFMA(2, 0,  Mre02, -Mim02)
        CFMA(2, 1, -Mre01,  Mim01)
        CFMA(2, 2,  Mre00, -Mim00)
        #undef CFMA
    }

    // incoherent sum, delta multiplicity {2,3,2}
    float s = 0.f;
    #pragma unroll
    for (int a = 0; a < 3; ++a) {
        s += 2.f * fmaf(Fre[a][0], Fre[a][0], Fim[a][0] * Fim[a][0]);
        s += 3.f * fmaf(Fre[a][1], Fre[a][1], Fim[a][1] * Fim[a][1]);
        s += 2.f * fmaf(Fre[a][2], Fre[a][2], Fim[a][2] * Fim[a][2]);
    }
    out[n] = s;
}

extern "C" void kernel_launch(void* const* d_in, const int* in_sizes, int n_in,
                              void* d_out, int out_size, void* d_ws, size_t ws_size,
                              hipStream_t stream)
{
    const float* a1 = (const float*)d_in[0];
    const float* b1 = (const float*)d_in[1];
    const float* g1 = (const float*)d_in[2];
    const float* a2 = (const float*)d_in[3];
    const float* b2 = (const float*)d_in[4];
    const float* g2 = (const float*)d_in[5];
    const float* m  = (const float*)d_in[6];
    const float* m0 = (const float*)d_in[7];
    const float* g0 = (const float*)d_in[8];
    const float* cr = (const float*)d_in[9];
    const float* ci = (const float*)d_in[10];
    float* out = (float*)d_out;

    const int N = out_size;               // 262144 events
    const int block = 256;
    const int grid = (N + block - 1) / block;
    amp_kernel<<<grid, block, 0, stream>>>(a1, b1, g1, a2, b2, g2, m, m0, g0, cr, ci, out, N);
}

// Round 3
// 92.915 us; speedup vs baseline: 1.0388x; 1.0189x over previous
//
#include <hip/hip_runtime.h>

#define RK 0.70710678118654752440f   // 1/sqrt(2)

__global__ __launch_bounds__(256) void amp_kernel(
    const float* __restrict__ a1, const float* __restrict__ b1, const float* __restrict__ g1,
    const float* __restrict__ a2, const float* __restrict__ b2, const float* __restrict__ g2,
    const float* __restrict__ mI, const float* __restrict__ m0, const float* __restrict__ g0,
    const float* __restrict__ cr, const float* __restrict__ ci,
    float* __restrict__ out, int N)
{
    const int t = blockIdx.x * blockDim.x + threadIdx.x;
    const int n0 = 2 * t;                 // this thread owns events n0, n0+1
    if (n0 >= N) return;

    // F[e][a][c]: coherent sum over resonances for event e.
    float Fre[2][3][3], Fim[2][3][3];
    #pragma unroll
    for (int e = 0; e < 2; ++e)
        #pragma unroll
        for (int a = 0; a < 3; ++a)
            #pragma unroll
            for (int c = 0; c < 3; ++c) { Fre[e][a][c] = 0.f; Fim[e][a][c] = 0.f; }

    #pragma unroll
    for (int r = 0; r < 4; ++r) {
        const int base = r * N + n0;      // N even -> float2-aligned
        const float2 A1 = *reinterpret_cast<const float2*>(a1 + base);
        const float2 B1 = *reinterpret_cast<const float2*>(b1 + base);
        const float2 G1 = *reinterpret_cast<const float2*>(g1 + base);
        const float2 A2 = *reinterpret_cast<const float2*>(a2 + base);
        const float2 B2 = *reinterpret_cast<const float2*>(b2 + base);
        const float2 G2 = *reinterpret_cast<const float2*>(g2 + base);
        const float2 MM = *reinterpret_cast<const float2*>(mI + base);

        // Per-resonance (event-independent) scalars — computed once, shared.
        const float m0r = m0[r], g0r = g0[r];
        const float m0sq = m0r * m0r;
        const float y = m0r * g0r;
        float sc, cc; __sincosf(ci[r], &sc, &cc);
        const float c_re = cr[r] * cc, c_im = cr[r] * sc;

        #pragma unroll
        for (int e = 0; e < 2; ++e) {
            const float vA1 = e ? A1.y : A1.x;
            const float vB1 = e ? B1.y : B1.x;
            const float vG1 = e ? G1.y : G1.x;
            const float vA2 = e ? A2.y : A2.x;
            const float vB2 = e ? B2.y : B2.x;
            const float vG2 = e ? G2.y : G2.x;
            const float mm  = e ? MM.y : MM.x;

            float sA, cA; __sincosf(vA1,       &sA, &cA);  // e^{i m1 alpha1}
            float sP, cP; __sincosf(vG1 + vA2, &sP, &cP);  // e^{i x (gamma1+alpha2)}
            float sG, cG; __sincosf(vG2,       &sG, &cG);  // e^{i delta gamma2}
            float sb1, cb1; __sincosf(vB1, &sb1, &cb1);
            float sb2, cb2; __sincosf(vB2, &sb2, &cb2);

            // Wigner small-d j=1 building blocks.
            const float hp1 = 0.5f * (1.f + cb1), hm1 = 0.5f * (1.f - cb1), ks1 = RK * sb1;
            const float hp2 = 0.5f * (1.f + cb2), hm2 = 0.5f * (1.f - cb2), ks2 = RK * sb2;

            // M[a][c] = sum_x d1[a][x] e^{i(x-1)phi} d2[x][c];
            // M[2-a][2-c] = (-1)^(a-c) conj(M[a][c]) -> compute 5 cells.
            float P0, P1, P2;
            P0 = hp1 * hp2;  P1 = -ks1 * ks2;  P2 = hm1 * hm2;
            const float Mre00 = fmaf(cP, P0 + P2, P1), Mim00 = sP * (P2 - P0);
            P0 = -hp1 * ks2; P1 = -ks1 * cb2;  P2 = hm1 * ks2;
            const float Mre01 = fmaf(cP, P0 + P2, P1), Mim01 = sP * (P2 - P0);
            P0 = hp1 * hm2;  P1 =  ks1 * ks2;  P2 = hm1 * hp2;
            const float Mre02 = fmaf(cP, P0 + P2, P1), Mim02 = sP * (P2 - P0);
            P0 = ks1 * hp2;  P1 =  cb1 * ks2;  P2 = -ks1 * hm2;
            const float Mre10 = fmaf(cP, P0 + P2, P1), Mim10 = sP * (P2 - P0);
            const float Mre11 = fmaf(-cP * sb1, sb2, cb1 * cb2);  // imag vanishes

            // W = coef * BW;  1/(x - i y) = (x + i y)/(x^2 + y^2)
            const float x = m0sq - mm * mm;
            const float inv = __builtin_amdgcn_rcpf(fmaf(x, x, y * y));
            const float bre = x * inv, bim = y * inv;
            const float Wre = c_re * bre - c_im * bim;
            const float Wim = c_re * bim + c_im * bre;

            // WA[a] = W * e^{i(a-1) alpha1}
            const float p1 = Wre * cA, p2 = Wim * sA, p3 = Wre * sA, p4 = Wim * cA;
            float WAre[3], WAim[3];
            WAre[0] = p1 + p2; WAim[0] = p4 - p3;
            WAre[1] = Wre;     WAim[1] = Wim;
            WAre[2] = p1 - p2; WAim[2] = p3 + p4;

            // q[a][c] = WA[a] * E[c], E = { e^{-i g2}, 1, e^{+i g2} }
            float qre[3][3], qim[3][3];
            #pragma unroll
            for (int a = 0; a < 3; ++a) {
                const float t1 = WAre[a] * cG, t2 = WAim[a] * sG;
                const float t3 = WAre[a] * sG, t4 = WAim[a] * cG;
                qre[a][0] = t1 + t2; qim[a][0] = t4 - t3;
                qre[a][1] = WAre[a]; qim[a][1] = WAim[a];
                qre[a][2] = t1 - t2; qim[a][2] = t3 + t4;
            }

            // F += q .* M  (derived cells via conjugate symmetry)
            #define CFMA(A, C, MRE, MIM)                                        \
                Fre[e][A][C] += qre[A][C] * (MRE) - qim[A][C] * (MIM);          \
                Fim[e][A][C] += qre[A][C] * (MIM) + qim[A][C] * (MRE);
            CFMA(0, 0,  Mre00,  Mim00)
            CFMA(0, 1,  Mre01,  Mim01)
            CFMA(0, 2,  Mre02,  Mim02)
            CFMA(1, 0,  Mre10,  Mim10)
            CFMA(1, 1,  Mre11,  0.f  )
            CFMA(1, 2, -Mre10,  Mim10)
            CFMA(2, 0,  Mre02, -Mim02)
            CFMA(2, 1, -Mre01,  Mim01)
            CFMA(2, 2,  Mre00, -Mim00)
            #undef CFMA
        }
    }

    // incoherent sum, delta multiplicity {2,3,2}; store both events as one dwordx2
    float2 res;
    #pragma unroll
    for (int e = 0; e < 2; ++e) {
        float s = 0.f;
        #pragma unroll
        for (int a = 0; a < 3; ++a) {
            s += 2.f * fmaf(Fre[e][a][0], Fre[e][a][0], Fim[e][a][0] * Fim[e][a][0]);
            s += 3.f * fmaf(Fre[e][a][1], Fre[e][a][1], Fim[e][a][1] * Fim[e][a][1]);
            s += 2.f * fmaf(Fre[e][a][2], Fre[e][a][2], Fim[e][a][2] * Fim[e][a][2]);
        }
        if (e) res.y = s; else res.x = s;
    }
    *reinterpret_cast<float2*>(out + n0) = res;
}

extern "C" void kernel_launch(void* const* d_in, const int* in_sizes, int n_in,
                              void* d_out, int out_size, void* d_ws, size_t ws_size,
                              hipStream_t stream)
{
    const float* a1 = (const float*)d_in[0];
    const float* b1 = (const float*)d_in[1];
    const float* g1 = (const float*)d_in[2];
    const float* a2 = (const float*)d_in[3];
    const float* b2 = (const float*)d_in[4];
    const float* g2 = (const float*)d_in[5];
    const float* m  = (const float*)d_in[6];
    const float* m0 = (const float*)d_in[7];
    const float* g0 = (const float*)d_in[8];
    const float* cr = (const float*)d_in[9];
    const float* ci = (const float*)d_in[10];
    float* out = (float*)d_out;

    const int N = out_size;               // 262144 events (even)
    const int block = 256;
    const int nthreads = N / 2;
    const int grid = (nthreads + block - 1) / block;
    amp_kernel<<<grid, block, 0, stream>>>(a1, b1, g1, a2, b2, g2, m, m0, g0, cr, ci, out, N);
}